// Round 8
// baseline (333.188 us; speedup 1.0000x reference)
//
#include <hip/hip_runtime.h>
#include <hip/hip_bf16.h>
#include <math.h>

typedef __attribute__((ext_vector_type(8))) unsigned short ushort8;
typedef __attribute__((ext_vector_type(8))) __bf16 bf16x8;
typedef __attribute__((ext_vector_type(4))) float floatx4;

constexpr int IMGW = 384;
constexpr int NPIX = IMGW * IMGW;

__device__ __forceinline__ unsigned short f2bf(float f) {
  union { float f; unsigned u; } v; v.f = f;
  unsigned u = v.u;
  return (unsigned short)((u + 0x7fffu + ((u >> 16) & 1u)) >> 16);
}
__device__ __forceinline__ float bf2f(unsigned short h) {
  union { unsigned u; float f; } v; v.u = ((unsigned)h) << 16; return v.f;
}
// pack 2 fp32 -> 2 bf16 (RNE): v_cvt_pk_bf16_f32
__device__ __forceinline__ unsigned pk2bf(float a, float b) {
  float2 f2; f2.x = a; f2.y = b;
  __hip_bfloat162 h = __float22bfloat162_rn(f2);
  union { __hip_bfloat162 h; unsigned u; } u; u.h = h; return u.u;
}
__device__ __forceinline__ floatx4 mfma16(bf16x8 a, bf16x8 b, floatx4 c) {
  return __builtin_amdgcn_mfma_f32_16x16x32_bf16(a, b, c, 0, 0, 0);
}
__device__ __forceinline__ bf16x8 lds_frag(const unsigned short* p) {
  return *reinterpret_cast<const bf16x8*>(p);
}
__device__ __forceinline__ bf16x8 u4_to_bf(uint4 v) {
  union { uint4 u; bf16x8 b; } c; c.u = v; return c.b;
}

// ---------------- fused weight prep (single launch) ----------------
__device__ __forceinline__ void convB_elem(const float* __restrict__ w,
                                           unsigned short* __restrict__ wt,
                                           int i, int CIN, int G, int NT) {
  int j = i & 7, lane = (i >> 3) & 63;
  int rest = i >> 9;
  int nt = rest % NT; int rest2 = rest / NT;
  int g = rest2 % G;  int ks = rest2 / G;
  int q = lane >> 4, m = lane & 15;
  int co = (g * NT + nt) * 16 + m;
  int k = ks * 32 + q * 8 + j;
  int nb = k / CIN, ci = k - nb * CIN;
  wt[i] = f2bf(w[(co * CIN + ci) * 9 + nb]);
}

// jobs: [0,29696) mlpA | cw1 147456 | cw2 147456 | cu1 73728 | cu2 36864 | cu3 9216
__global__ __launch_bounds__(256) void prep_all(
    const float* __restrict__ w1, const float* __restrict__ w2, const float* __restrict__ w3,
    const float* __restrict__ mw1, const float* __restrict__ mw2,
    const float* __restrict__ uw1, const float* __restrict__ uw2,
    const float* __restrict__ uw3,
    unsigned short* __restrict__ w1A, unsigned short* __restrict__ w2A,
    unsigned short* __restrict__ w3A,
    unsigned short* __restrict__ cw1, unsigned short* __restrict__ cw2,
    unsigned short* __restrict__ cu1, unsigned short* __restrict__ cu2,
    unsigned short* __restrict__ cu3) {
  int i = blockIdx.x * 256 + threadIdx.x;
  if (i < 29696) {
    if (i < 8192) {                       // w1A: M=128 (mt 8), KS=2
      int j = i & 7, lane = (i >> 3) & 63, t = i >> 9;
      int mt = t >> 1, ks = t & 1;
      int ch_out = mt * 16 + (lane & 15);
      int kp = ks * 32 + (lane >> 4) * 8 + j;
      int chunk = kp >> 3, sl = kp & 7;
      float val;
      if (chunk == 7 && sl >= 4) {
        int c = sl - 4;
        val = (c < 3) ? w1[c * 128 + ch_out] : 0.0f;   // raw x,y,z,pad
      } else {
        const int coordA[8] = {0,0,0,1,1,2,2,2};
        const int octA[8]   = {0,4,8,2,6,0,4,8};
        const int coordB[8] = {0,0,1,1,1,2,2,2};
        const int octB[8]   = {2,6,0,4,8,2,6,0};
        int rc  = (sl < 4) ? coordA[chunk] : coordB[chunk];
        int oct = ((sl < 4) ? octA[chunk] : octB[chunk]) + ((sl >> 1) & 1);
        int korig = ((sl & 1) ? 33 : 3) + rc * 10 + oct;
        val = w1[korig * 128 + ch_out];
      }
      w1A[i] = f2bf(val);
    } else if (i < 24576) {               // w2A: M=128 (mt 8), KS=4, permuted k
      int i2 = i - 8192;
      int j = i2 & 7, lane = (i2 >> 3) & 63, t = i2 >> 9;
      int mt = t >> 2, ks = t & 3;
      int ch_out = mt * 16 + (lane & 15);
      int kp = ks * 32 + (lane >> 4) * 8 + j;
      int c_orig = ((kp >> 2) & 7) * 16 + (kp >> 5) * 4 + (kp & 3);
      w2A[i2] = f2bf(w2[c_orig * 128 + ch_out]);
    } else {                              // w3A: M=32 (mt 2), KS=5 (4 hidden + dpe), stride-8 ks slots
      int i3 = i - 24576;                 // [0, 5120)
      int j = i3 & 7, lane = (i3 >> 3) & 63, t = i3 >> 9;   // t in [0,10)
      int mt = (t >= 5) ? 1 : 0; int ks = t - mt * 5;
      int q = lane >> 4, m = lane & 15;
      int ch_out = mt * 16 + m;
      float val;
      if (ks < 4) {                       // hidden K, permuted
        int kp = ks * 32 + q * 8 + j;
        int c_orig = ((kp >> 2) & 7) * 16 + (kp >> 5) * 4 + (kp & 3);
        val = w3[c_orig * 32 + ch_out];
      } else {                            // dpe K-block: slot layout co-designed with mlp prologue
        int row = -1;
        if (q == 0) {
          if (j < 3) row = 128 + j;                       // raw d0,d1,d2
          else if (j >= 4) {
            int ga = (j - 4) >> 1;                        // angles 0,1
            row = (((j - 4) & 1) == 0 ? 131 : 143) + ga;  // sin/cos pair
          }
        } else {
          int ga = q * 4 - 2 + (j >> 1);                  // q1:2..5 q2:6..9 q3:10..13
          if (ga < 12) row = ((j & 1) == 0 ? 131 : 143) + ga;
        }
        val = (row >= 0) ? w3[row * 32 + ch_out] : 0.0f;
      }
      w3A[(((mt << 3) + ks) << 9) + (lane << 3) + j] = f2bf(val);
    }
    return;
  }
  i -= 29696;
  if (i < 147456) { convB_elem(mw1, cw1, i, 128, 4, 2); return; }
  i -= 147456;
  if (i < 147456) { convB_elem(mw2, cw2, i, 128, 4, 2); return; }
  i -= 147456;
  if (i < 73728)  { convB_elem(uw1, cu1, i, 128, 4, 1); return; }
  i -= 73728;
  if (i < 36864)  { convB_elem(uw2, cu2, i, 64, 4, 1); return; }
  i -= 36864;
  {                                       // cu3: uw3 (3->16 padded couts), CIN=64, KS=18
    int j = i & 7, lane = (i >> 3) & 63, ks = i >> 9;
    int q = lane >> 4, m = lane & 15;
    int k = ks * 32 + q * 8 + j;
    int nb = k >> 6, ci = k & 63;
    float val = (m < 3) ? uw3[(m * 64 + ci) * 9 + nb] : 0.0f;
    cu3[i] = f2bf(val);
  }
}

// ---------------- fused per-sample MLP (R17 config, byte-identical) ---------
__global__ __launch_bounds__(128, 4) void mlp_kernel(
    const float* __restrict__ zbufs, const float* __restrict__ ray,
    const int* __restrict__ isTrain,
    const float* __restrict__ b1, const float* __restrict__ b2,
    const float* __restrict__ b3,
    const unsigned short* __restrict__ w1A, const unsigned short* __restrict__ w2A,
    const unsigned short* __restrict__ w3A,
    unsigned short* __restrict__ rdmp) {
  __shared__ __align__(16) unsigned short H[64 * 136];

  const int tid = threadIdx.x;
  const int half = tid >> 6;          // wave id = cout-half (L1/L2), sample-half (L3)
  const int lane = tid & 63;
  const int q = lane >> 4, m = lane & 15;
  const float thresh = (isTrain[0] != 0) ? 0.2f : 0.0f;

  float fA[2], fB[2];
  int cAi[2], cBi[2];
  #pragma unroll
  for (int ks = 0; ks < 2; ++ks) {
    int ch = ks * 4 + q;
    cAi[ks] = (ch <= 2) ? 0 : ((ch <= 4) ? 1 : 2);
    fA[ks]  = (ch == 0 || ch == 5) ? 1.0f :
              (ch == 1 || ch == 6) ? 16.0f :
              (ch == 2 || ch == 7) ? 256.0f :
              (ch == 3) ? 4.0f : 64.0f;
    cBi[ks] = (ch <= 1) ? 0 : ((ch <= 4) ? 1 : 2);
    fB[ks]  = (ch == 2) ? 1.0f :
              (ch == 0 || ch == 5) ? 4.0f :
              (ch == 3) ? 16.0f :
              (ch == 1 || ch == 6) ? 64.0f : 256.0f;
  }

  bf16x8 bx[4][2];
  bf16x8 dpe0, dpe1;
  float zs[4];
  #pragma unroll
  for (int nt = 0; nt < 4; ++nt) {
    int s = nt * 16 + m;
    int sg = blockIdx.x * 64 + s;
    int pixel = sg >> 2;
    float z = zbufs[sg];
    zs[nt] = z;
    const float* r = ray + (size_t)pixel * 7;
    float t = z / r[6];
    float xv0 = r[0] + r[3] * t, xv1 = r[1] + r[4] * t, xv2 = r[2] + r[5] * t;
    #pragma unroll
    for (int ks = 0; ks < 2; ++ks) {
      float uA = (cAi[ks] == 0) ? xv0 : ((cAi[ks] == 1) ? xv1 : xv2);
      float uB = (cBi[ks] == 0) ? xv0 : ((cBi[ks] == 1) ? xv1 : xv2);
      float sa, ca, sb, cb;
      __sincosf(uA * fA[ks], &sa, &ca);
      __sincosf(uB * fB[ks], &sb, &cb);
      float t2a = sa + sa;
      float sa1 = t2a * ca, ca1 = fmaf(-t2a, sa, 1.0f);
      float t2b = sb + sb;
      float sb1 = t2b * cb, cb1 = fmaf(-t2b, sb, 1.0f);
      if (ks == 1 && q == 3) { sb = xv0; cb = xv1; sb1 = xv2; cb1 = 0.0f; }
      uint4 dv;
      dv.x = pk2bf(sa, ca); dv.y = pk2bf(sa1, ca1);
      dv.z = pk2bf(sb, cb); dv.w = pk2bf(sb1, cb1);
      bx[nt][ks] = u4_to_bf(dv);
    }
    // dir-PE fragment for this wave's two L3 sample groups
    if ((nt >> 1) == half) {
      float dd0 = r[3], dd1 = r[4], dd2 = r[5];
      float ss[4], cc[4];
      #pragma unroll
      for (int ii = 0; ii < 4; ++ii) {
        int a = q * 4 + ii - 2;                 // angle index; <0 or >11 = dummy
        int ac = (a < 0 || a > 11) ? 0 : a;
        int c = ac >> 2;
        float base = (c == 0) ? dd0 : ((c == 1) ? dd1 : dd2);
        float fs = (float)(1 << (ac & 3));
        __sincosf(base * fs, &ss[ii], &cc[ii]);
      }
      uint4 dv;
      if (q == 0) {
        dv.x = pk2bf(dd0, dd1);
        dv.y = pk2bf(dd2, 0.0f);
        dv.z = pk2bf(ss[2], cc[2]);
        dv.w = pk2bf(ss[3], cc[3]);
      } else if (q == 3) {
        dv.x = pk2bf(ss[0], cc[0]);
        dv.y = pk2bf(ss[1], cc[1]);
        dv.z = 0u; dv.w = 0u;
      } else {
        dv.x = pk2bf(ss[0], cc[0]);
        dv.y = pk2bf(ss[1], cc[1]);
        dv.z = pk2bf(ss[2], cc[2]);
        dv.w = pk2bf(ss[3], cc[3]);
      }
      if ((nt & 1) == 0) dpe0 = u4_to_bf(dv); else dpe1 = u4_to_bf(dv);
    }
  }
  // L3 sample-half z values (constant-index selects)
  float zL[2];
  zL[0] = (half == 0) ? zs[0] : zs[2];
  zL[1] = (half == 0) ? zs[1] : zs[3];

  // ---- layer 1: this wave's cout-half ----
  {
    floatx4 acc[4][4];
    #pragma unroll
    for (int mt = 0; mt < 4; ++mt) {
      float4 bb = *reinterpret_cast<const float4*>(b1 + (half * 4 + mt) * 16 + q * 4);
      #pragma unroll
      for (int nt = 0; nt < 4; ++nt) {
        acc[mt][nt][0] = bb.x; acc[mt][nt][1] = bb.y;
        acc[mt][nt][2] = bb.z; acc[mt][nt][3] = bb.w;
      }
    }
    #pragma unroll
    for (int ks = 0; ks < 2; ++ks) {
      #pragma unroll
      for (int mt = 0; mt < 4; ++mt) {
        int mtg = half * 4 + mt;
        bf16x8 a = *reinterpret_cast<const bf16x8*>(w1A + (((mtg << 1) + ks) << 9) + lane * 8);
        #pragma unroll
        for (int nt = 0; nt < 4; ++nt)
          acc[mt][nt] = mfma16(a, bx[nt][ks], acc[mt][nt]);
      }
    }
    #pragma unroll
    for (int nt = 0; nt < 4; ++nt) {
      uint4* base = reinterpret_cast<uint4*>(&H[(nt * 16 + m) * 136 + q * 32 + half * 16]);
      #pragma unroll
      for (int g = 0; g < 2; ++g) {
        uint4 v;
        v.x = pk2bf(fmaxf(acc[2*g][nt][0], 0.0f),   fmaxf(acc[2*g][nt][1], 0.0f));
        v.y = pk2bf(fmaxf(acc[2*g][nt][2], 0.0f),   fmaxf(acc[2*g][nt][3], 0.0f));
        v.z = pk2bf(fmaxf(acc[2*g+1][nt][0], 0.0f), fmaxf(acc[2*g+1][nt][1], 0.0f));
        v.w = pk2bf(fmaxf(acc[2*g+1][nt][2], 0.0f), fmaxf(acc[2*g+1][nt][3], 0.0f));
        base[g] = v;
      }
    }
  }
  __syncthreads();   // h1 complete before L2 reads

  // ---- layer 2: this wave's cout-half; epilogue staged in regs ----
  {
    uint4 keep[4][2];
    {
      floatx4 acc[4][4];
      #pragma unroll
      for (int mt = 0; mt < 4; ++mt) {
        float4 bb = *reinterpret_cast<const float4*>(b2 + (half * 4 + mt) * 16 + q * 4);
        #pragma unroll
        for (int nt = 0; nt < 4; ++nt) {
          acc[mt][nt][0] = bb.x; acc[mt][nt][1] = bb.y;
          acc[mt][nt][2] = bb.z; acc[mt][nt][3] = bb.w;
        }
      }
      #pragma unroll 1
      for (int ks = 0; ks < 4; ++ks) {
        bf16x8 bf[4];
        #pragma unroll
        for (int nt = 0; nt < 4; ++nt)
          bf[nt] = lds_frag(H + (nt * 16 + m) * 136 + ks * 32 + q * 8);
        #pragma unroll
        for (int mt = 0; mt < 4; ++mt) {
          int mtg = half * 4 + mt;
          bf16x8 a = *reinterpret_cast<const bf16x8*>(w2A + (((mtg << 2) + ks) << 9) + lane * 8);
          #pragma unroll
          for (int nt = 0; nt < 4; ++nt)
            acc[mt][nt] = mfma16(a, bf[nt], acc[mt][nt]);
        }
      }
      #pragma unroll
      for (int nt = 0; nt < 4; ++nt) {
        #pragma unroll
        for (int g = 0; g < 2; ++g) {
          uint4 v;
          v.x = pk2bf(fmaxf(acc[2*g][nt][0], 0.0f),   fmaxf(acc[2*g][nt][1], 0.0f));
          v.y = pk2bf(fmaxf(acc[2*g][nt][2], 0.0f),   fmaxf(acc[2*g][nt][3], 0.0f));
          v.z = pk2bf(fmaxf(acc[2*g+1][nt][0], 0.0f), fmaxf(acc[2*g+1][nt][1], 0.0f));
          v.w = pk2bf(fmaxf(acc[2*g+1][nt][2], 0.0f), fmaxf(acc[2*g+1][nt][3], 0.0f));
          keep[nt][g] = v;
        }
      }
    }
    __syncthreads();   // all h1 reads done before overwrite
    #pragma unroll
    for (int nt = 0; nt < 4; ++nt)
      #pragma unroll
      for (int g = 0; g < 2; ++g)
        *reinterpret_cast<uint4*>(&H[(nt * 16 + m) * 136 + q * 32 + half * 16 + g * 8]) = keep[nt][g];
  }
  __syncthreads();   // h2 complete before L3 reads

  // ---- layer 3: both cout-tiles, this wave's sample-half; K = 128 hidden + 27 dpe ----
  {
    floatx4 acc[2][2];   // [mt][nt2]
    #pragma unroll
    for (int mt = 0; mt < 2; ++mt) {
      float4 bb3 = *reinterpret_cast<const float4*>(b3 + mt * 16 + q * 4);
      #pragma unroll
      for (int nt2 = 0; nt2 < 2; ++nt2) {
        acc[mt][nt2][0] = bb3.x; acc[mt][nt2][1] = bb3.y;
        acc[mt][nt2][2] = bb3.z; acc[mt][nt2][3] = bb3.w;
      }
    }
    #pragma unroll
    for (int mt = 0; mt < 2; ++mt) {      // dpe K-block (ks slot 4)
      bf16x8 a = *reinterpret_cast<const bf16x8*>(w3A + (((mt << 3) + 4) << 9) + lane * 8);
      acc[mt][0] = mfma16(a, dpe0, acc[mt][0]);
      acc[mt][1] = mfma16(a, dpe1, acc[mt][1]);
    }
    #pragma unroll 2
    for (int ks = 0; ks < 4; ++ks) {
      bf16x8 bf[2];
      #pragma unroll
      for (int nt2 = 0; nt2 < 2; ++nt2)
        bf[nt2] = lds_frag(H + ((half * 2 + nt2) * 16 + m) * 136 + ks * 32 + q * 8);
      #pragma unroll
      for (int mt = 0; mt < 2; ++mt) {
        bf16x8 a = *reinterpret_cast<const bf16x8*>(w3A + (((mt << 3) + ks) << 9) + lane * 8);
        #pragma unroll
        for (int nt2 = 0; nt2 < 2; ++nt2)
          acc[mt][nt2] = mfma16(a, bf[nt2], acc[mt][nt2]);
      }
    }
    #pragma unroll
    for (int nt2 = 0; nt2 < 2; ++nt2) {
      int s = (half * 2 + nt2) * 16 + m;
      float mk = (zL[nt2] > thresh) ? 1.0f : 0.0f;
      unsigned short* dst = rdmp + (size_t)blockIdx.x * 2048 + s * 32 + q * 4;
      #pragma unroll
      for (int mt = 0; mt < 2; ++mt) {
        uint2 pk;
        pk.x = pk2bf(acc[mt][nt2][0] * mk, acc[mt][nt2][1] * mk);
        pk.y = pk2bf(acc[mt][nt2][2] * mk, acc[mt][nt2][3] * mk);
        *reinterpret_cast<uint2*>(dst + mt * 16) = pk;
      }
    }
  }
}

// ---------------- conv tile: fully-unrolled g-loop (R18 theory, R20 plain) ---
// R19's cooperative wrapper hung the container (grid.sync risk); the unroll
// hypothesis is testable with ordinary launches. kc/dx constant after unroll:
// LDS reads = base+imm, B addresses strength-reduce, no ping-pong copy.
template<int CIN, int COUT, int MODE>
__device__ __forceinline__ void conv_tile(
    int tile,
    const unsigned short* in, const unsigned short* wt,
    const float* bias, const unsigned short* rdmp,
    unsigned short* out, unsigned short* lds_in) {
  constexpr int CP  = CIN + 8;
  constexpr int CH8 = CIN / 8;
  constexpr int KC  = CIN / 32;
  constexpr int NT  = COUT / 64;
  constexpr int GROUPS = KC * 3;
  const int tid = threadIdx.x;
  const int x0 = (tile % 24) * 16, y0 = (tile / 24) * 8;

  for (int i = tid; i < 180 * CH8; i += 512) {
    int pix = i / CH8, part = i - pix * CH8;    // CH8 is pow2
    int xx = pix % 18, yy = pix / 18;
    int gx = x0 - 1 + xx, gy = y0 - 1 + yy;
    ushort8 v = {0, 0, 0, 0, 0, 0, 0, 0};
    if (gx >= 0 && gx < IMGW && gy >= 0 && gy < IMGW)
      v = *reinterpret_cast<const ushort8*>(in + ((size_t)(gy * IMGW + gx)) * CIN + part * 8);
    *reinterpret_cast<ushort8*>(&lds_in[pix * CP + part * 8]) = v;
  }
  __syncthreads();

  const int wave = tid >> 6, lane = tid & 63, q = lane >> 4, m = lane & 15;
  const int cw = wave & 3;       // cout quarter
  const int rw = wave >> 2;      // row half: output rows rw*4 .. rw*4+3
  floatx4 acc[4][NT] = {};

  #pragma unroll
  for (int g = 0; g < GROUPS; ++g) {
    const int kc = g / 3, dx = g % 3;           // constants after unroll
    bf16x8 b[3][NT];
    #pragma unroll
    for (int dy = 0; dy < 3; ++dy) {
      const int ks = (dy * 3 + dx) * KC + kc;
      #pragma unroll
      for (int nt = 0; nt < NT; ++nt)
        b[dy][nt] = *reinterpret_cast<const bf16x8*>(
            wt + ((((size_t)ks * 4 + cw) * NT + nt) << 9) + lane * 8);
    }
    bf16x8 a[6];
    #pragma unroll
    for (int rr = 0; rr < 6; ++rr)
      a[rr] = lds_frag(&lds_in[((rw * 4 + rr) * 18 + m + dx) * CP + kc * 32 + q * 8]);
    #pragma unroll
    for (int dy = 0; dy < 3; ++dy)
      #pragma unroll
      for (int nt = 0; nt < NT; ++nt)
        #pragma unroll
        for (int mt = 0; mt < 4; ++mt)
          acc[mt][nt] = mfma16(a[mt + dy], b[dy][nt], acc[mt][nt]);
  }

  const int co0 = cw * (COUT / 4);
  #pragma unroll
  for (int mt = 0; mt < 4; ++mt) {
    int y = y0 + rw * 4 + mt;
    #pragma unroll
    for (int nt = 0; nt < NT; ++nt) {
      int co = co0 + nt * 16 + m;
      float bb = bias[co];
      #pragma unroll
      for (int r = 0; r < 4; ++r) {
        int pixel = y * IMGW + x0 + q * 4 + r;
        float v = acc[mt][nt][r] + bb;
        if (MODE == 0) {
          v = fmaxf(v, 0.0f);
        } else {
          v = 1.0f / (1.0f + __expf(-v));
          v *= bf2f(rdmp[(size_t)pixel * 128 + co]);
        }
        out[(size_t)pixel * COUT + co] = f2bf(v);
      }
    }
  }
}

// final 64->3 conv + sigmoid, 8 waves x 1 row, fully unrolled
__device__ __forceinline__ void uconv_tile(
    int tile, const unsigned short* u2, const unsigned short* wt,
    const float* b, float* out, unsigned short* lds_in) {
  const int tid = threadIdx.x;
  const int x0 = (tile % 24) * 16, y0 = (tile / 24) * 8;
  for (int i = tid; i < 180 * 8; i += 512) {
    int pix = i >> 3, part = i & 7;
    int xx = pix % 18, yy = pix / 18;
    int gx = x0 - 1 + xx, gy = y0 - 1 + yy;
    ushort8 v = {0, 0, 0, 0, 0, 0, 0, 0};
    if (gx >= 0 && gx < IMGW && gy >= 0 && gy < IMGW)
      v = *reinterpret_cast<const ushort8*>(u2 + (size_t)(gy * IMGW + gx) * 64 + part * 8);
    *reinterpret_cast<ushort8*>(&lds_in[pix * 72 + part * 8]) = v;
  }
  __syncthreads();
  const int wave = tid >> 6, lane = tid & 63, q = lane >> 4, m = lane & 15;
  floatx4 acc = {};
  #pragma unroll
  for (int g = 0; g < 6; ++g) {
    const int kc = g / 3, dx = g % 3;
    bf16x8 bb[3];
    #pragma unroll
    for (int dy = 0; dy < 3; ++dy)
      bb[dy] = *reinterpret_cast<const bf16x8*>(wt + ((((dy * 3 + dx) * 2) + kc) << 9) + lane * 8);
    bf16x8 a[3];
    #pragma unroll
    for (int dy = 0; dy < 3; ++dy)
      a[dy] = lds_frag(&lds_in[((wave + dy) * 18 + m + dx) * 72 + kc * 32 + q * 8]);
    #pragma unroll
    for (int dy = 0; dy < 3; ++dy)
      acc = mfma16(a[dy], bb[dy], acc);
  }
  if (m < 3) {
    float bbv = b[m];
    int y = y0 + wave;
    #pragma unroll
    for (int r = 0; r < 4; ++r) {
      int pixel = y * IMGW + x0 + q * 4 + r;
      out[(size_t)pixel * 3 + m] = 1.0f / (1.0f + __expf(-(acc[r] + bbv)));
    }
  }
}

// ---------------- plain-launch wrappers -------------------------------------
template<int CIN, int COUT, int MODE>
__global__ __launch_bounds__(512, 4) void conv_wrap(
    const unsigned short* __restrict__ in, const unsigned short* __restrict__ wt,
    const float* __restrict__ bias, const unsigned short* __restrict__ rdmp,
    unsigned short* __restrict__ out) {
  __shared__ __align__(16) unsigned short lds[10 * 18 * (CIN + 8)];
  conv_tile<CIN, COUT, MODE>(blockIdx.x, in, wt, bias, rdmp, out, lds);
}
__global__ __launch_bounds__(512, 4) void uconv_wrap(
    const unsigned short* __restrict__ u2, const unsigned short* __restrict__ wt,
    const float* __restrict__ b, float* __restrict__ out) {
  __shared__ __align__(16) unsigned short lds[180 * 72];
  uconv_tile(blockIdx.x, u2, wt, b, out, lds);
}

extern "C" void kernel_launch(void* const* d_in, const int* in_sizes, int n_in,
                              void* d_out, int out_size, void* d_ws, size_t ws_size,
                              hipStream_t stream) {
  (void)in_sizes; (void)n_in; (void)out_size; (void)ws_size;
  const float* zbufs = (const float*)d_in[0];
  const float* ray   = (const float*)d_in[1];
  const int* isTrain = (const int*)d_in[4];
  const float* w1 = (const float*)d_in[6];
  const float* b1 = (const float*)d_in[7];
  const float* w2 = (const float*)d_in[8];
  const float* b2 = (const float*)d_in[9];
  const float* w3 = (const float*)d_in[10];
  const float* b3 = (const float*)d_in[11];
  const float* mpn_w1 = (const float*)d_in[12];
  const float* mpn_b1 = (const float*)d_in[13];
  const float* mpn_w2 = (const float*)d_in[14];
  const float* mpn_b2 = (const float*)d_in[15];
  const float* uw1 = (const float*)d_in[16];
  const float* ub1 = (const float*)d_in[17];
  const float* uw2 = (const float*)d_in[18];
  const float* ub2 = (const float*)d_in[19];
  const float* uw3 = (const float*)d_in[20];
  const float* ub3 = (const float*)d_in[21];
  float* out = (float*)d_out;

  unsigned char* ws = (unsigned char*)d_ws;
  size_t off = 0;
  auto alloc = [&](size_t bytes) -> void* {
    void* p = ws + off; off = (off + bytes + 255) & ~(size_t)255; return p;
  };
  unsigned short* w1A  = (unsigned short*)alloc(8192 * 2);
  unsigned short* w2A  = (unsigned short*)alloc(16384 * 2);
  unsigned short* w3A  = (unsigned short*)alloc(8192 * 2);
  unsigned short* cw1  = (unsigned short*)alloc((size_t)128 * 1152 * 2);
  unsigned short* cw2  = (unsigned short*)alloc((size_t)128 * 1152 * 2);
  unsigned short* cu1  = (unsigned short*)alloc((size_t)64 * 1152 * 2);
  unsigned short* cu2  = (unsigned short*)alloc((size_t)64 * 576 * 2);
  unsigned short* cu3  = (unsigned short*)alloc((size_t)9216 * 2);
  unsigned short* rdmp = (unsigned short*)alloc((size_t)NPIX * 128 * 2);
  unsigned short* t1   = (unsigned short*)alloc((size_t)NPIX * 128 * 2);
  unsigned short* fuse = (unsigned short*)alloc((size_t)NPIX * 128 * 2);
  unsigned short* u1 = t1;            // t1 dead after conv2
  unsigned short* u2 = rdmp;          // rdmp dead after conv2 (fuse epilogue)

  prep_all<<<1736, 256, 0, stream>>>(w1, w2, w3, mpn_w1, mpn_w2, uw1, uw2, uw3,
                                     w1A, w2A, w3A, cw1, cw2, cu1, cu2, cu3);
  mlp_kernel<<<NPIX * 4 / 64, 128, 0, stream>>>(zbufs, ray, isTrain, b1, b2, b3,
                                                w1A, w2A, w3A, rdmp);

  conv_wrap<128, 128, 0><<<1152, 512, 0, stream>>>(rdmp, cw1, mpn_b1, nullptr, t1);
  conv_wrap<128, 128, 1><<<1152, 512, 0, stream>>>(t1, cw2, mpn_b2, rdmp, fuse);
  conv_wrap<128, 64, 0><<<1152, 512, 0, stream>>>(fuse, cu1, ub1, nullptr, u1);
  conv_wrap<64, 64, 0><<<1152, 512, 0, stream>>>(u1, cu2, ub2, nullptr, u2);
  uconv_wrap<<<1152, 512, 0, stream>>>(u2, cu3, ub3, out);
}

// Round 9
// 292.426 us; speedup vs baseline: 1.1394x; 1.1394x over previous
//
#include <hip/hip_runtime.h>
#include <hip/hip_bf16.h>
#include <math.h>

typedef __attribute__((ext_vector_type(8))) unsigned short ushort8;
typedef __attribute__((ext_vector_type(8))) __bf16 bf16x8;
typedef __attribute__((ext_vector_type(4))) float floatx4;

constexpr int IMGW = 384;
constexpr int NPIX = IMGW * IMGW;

__device__ __forceinline__ unsigned short f2bf(float f) {
  union { float f; unsigned u; } v; v.f = f;
  unsigned u = v.u;
  return (unsigned short)((u + 0x7fffu + ((u >> 16) & 1u)) >> 16);
}
__device__ __forceinline__ float bf2f(unsigned short h) {
  union { unsigned u; float f; } v; v.u = ((unsigned)h) << 16; return v.f;
}
// pack 2 fp32 -> 2 bf16 (RNE): v_cvt_pk_bf16_f32
__device__ __forceinline__ unsigned pk2bf(float a, float b) {
  float2 f2; f2.x = a; f2.y = b;
  __hip_bfloat162 h = __float22bfloat162_rn(f2);
  union { __hip_bfloat162 h; unsigned u; } u; u.h = h; return u.u;
}
__device__ __forceinline__ floatx4 mfma16(bf16x8 a, bf16x8 b, floatx4 c) {
  return __builtin_amdgcn_mfma_f32_16x16x32_bf16(a, b, c, 0, 0, 0);
}
__device__ __forceinline__ bf16x8 lds_frag(const unsigned short* p) {
  return *reinterpret_cast<const bf16x8*>(p);
}
__device__ __forceinline__ bf16x8 u4_to_bf(uint4 v) {
  union { uint4 u; bf16x8 b; } c; c.u = v; return c.b;
}

// ---------------- fused weight prep (single launch) ----------------
__device__ __forceinline__ void convB_elem(const float* __restrict__ w,
                                           unsigned short* __restrict__ wt,
                                           int i, int CIN, int G, int NT) {
  int j = i & 7, lane = (i >> 3) & 63;
  int rest = i >> 9;
  int nt = rest % NT; int rest2 = rest / NT;
  int g = rest2 % G;  int ks = rest2 / G;
  int q = lane >> 4, m = lane & 15;
  int co = (g * NT + nt) * 16 + m;
  int k = ks * 32 + q * 8 + j;
  int nb = k / CIN, ci = k - nb * CIN;
  wt[i] = f2bf(w[(co * CIN + ci) * 9 + nb]);
}

// jobs: [0,29696) mlpA | cw1 147456 | cw2 147456 | cu1 73728 | cu2 36864 | cu3 9216
__global__ __launch_bounds__(256) void prep_all(
    const float* __restrict__ w1, const float* __restrict__ w2, const float* __restrict__ w3,
    const float* __restrict__ mw1, const float* __restrict__ mw2,
    const float* __restrict__ uw1, const float* __restrict__ uw2,
    const float* __restrict__ uw3,
    unsigned short* __restrict__ w1A, unsigned short* __restrict__ w2A,
    unsigned short* __restrict__ w3A,
    unsigned short* __restrict__ cw1, unsigned short* __restrict__ cw2,
    unsigned short* __restrict__ cu1, unsigned short* __restrict__ cu2,
    unsigned short* __restrict__ cu3) {
  int i = blockIdx.x * 256 + threadIdx.x;
  if (i < 29696) {
    if (i < 8192) {                       // w1A: M=128 (mt 8), KS=2
      int j = i & 7, lane = (i >> 3) & 63, t = i >> 9;
      int mt = t >> 1, ks = t & 1;
      int ch_out = mt * 16 + (lane & 15);
      int kp = ks * 32 + (lane >> 4) * 8 + j;
      int chunk = kp >> 3, sl = kp & 7;
      float val;
      if (chunk == 7 && sl >= 4) {
        int c = sl - 4;
        val = (c < 3) ? w1[c * 128 + ch_out] : 0.0f;   // raw x,y,z,pad
      } else {
        const int coordA[8] = {0,0,0,1,1,2,2,2};
        const int octA[8]   = {0,4,8,2,6,0,4,8};
        const int coordB[8] = {0,0,1,1,1,2,2,2};
        const int octB[8]   = {2,6,0,4,8,2,6,0};
        int rc  = (sl < 4) ? coordA[chunk] : coordB[chunk];
        int oct = ((sl < 4) ? octA[chunk] : octB[chunk]) + ((sl >> 1) & 1);
        int korig = ((sl & 1) ? 33 : 3) + rc * 10 + oct;
        val = w1[korig * 128 + ch_out];
      }
      w1A[i] = f2bf(val);
    } else if (i < 24576) {               // w2A: M=128 (mt 8), KS=4, permuted k
      int i2 = i - 8192;
      int j = i2 & 7, lane = (i2 >> 3) & 63, t = i2 >> 9;
      int mt = t >> 2, ks = t & 3;
      int ch_out = mt * 16 + (lane & 15);
      int kp = ks * 32 + (lane >> 4) * 8 + j;
      int c_orig = ((kp >> 2) & 7) * 16 + (kp >> 5) * 4 + (kp & 3);
      w2A[i2] = f2bf(w2[c_orig * 128 + ch_out]);
    } else {                              // w3A: M=32 (mt 2), KS=5 (4 hidden + dpe), stride-8 ks slots
      int i3 = i - 24576;                 // [0, 5120)
      int j = i3 & 7, lane = (i3 >> 3) & 63, t = i3 >> 9;   // t in [0,10)
      int mt = (t >= 5) ? 1 : 0; int ks = t - mt * 5;
      int q = lane >> 4, m = lane & 15;
      int ch_out = mt * 16 + m;
      float val;
      if (ks < 4) {                       // hidden K, permuted
        int kp = ks * 32 + q * 8 + j;
        int c_orig = ((kp >> 2) & 7) * 16 + (kp >> 5) * 4 + (kp & 3);
        val = w3[c_orig * 32 + ch_out];
      } else {                            // dpe K-block: slot layout co-designed with mlp prologue
        int row = -1;
        if (q == 0) {
          if (j < 3) row = 128 + j;                       // raw d0,d1,d2
          else if (j >= 4) {
            int ga = (j - 4) >> 1;                        // angles 0,1
            row = (((j - 4) & 1) == 0 ? 131 : 143) + ga;  // sin/cos pair
          }
        } else {
          int ga = q * 4 - 2 + (j >> 1);                  // q1:2..5 q2:6..9 q3:10..13
          if (ga < 12) row = ((j & 1) == 0 ? 131 : 143) + ga;
        }
        val = (row >= 0) ? w3[row * 32 + ch_out] : 0.0f;
      }
      w3A[(((mt << 3) + ks) << 9) + (lane << 3) + j] = f2bf(val);
    }
    return;
  }
  i -= 29696;
  if (i < 147456) { convB_elem(mw1, cw1, i, 128, 4, 2); return; }
  i -= 147456;
  if (i < 147456) { convB_elem(mw2, cw2, i, 128, 4, 2); return; }
  i -= 147456;
  if (i < 73728)  { convB_elem(uw1, cu1, i, 128, 4, 1); return; }
  i -= 73728;
  if (i < 36864)  { convB_elem(uw2, cu2, i, 64, 4, 1); return; }
  i -= 36864;
  {                                       // cu3: uw3 (3->16 padded couts), CIN=64, KS=18
    int j = i & 7, lane = (i >> 3) & 63, ks = i >> 9;
    int q = lane >> 4, m = lane & 15;
    int k = ks * 32 + q * 8 + j;
    int nb = k >> 6, ci = k & 63;
    float val = (m < 3) ? uw3[(m * 64 + ci) * 9 + nb] : 0.0f;
    cu3[i] = f2bf(val);
  }
}

// ---------------- fused per-sample MLP (R17 config, byte-identical) ---------
__global__ __launch_bounds__(128, 4) void mlp_kernel(
    const float* __restrict__ zbufs, const float* __restrict__ ray,
    const int* __restrict__ isTrain,
    const float* __restrict__ b1, const float* __restrict__ b2,
    const float* __restrict__ b3,
    const unsigned short* __restrict__ w1A, const unsigned short* __restrict__ w2A,
    const unsigned short* __restrict__ w3A,
    unsigned short* __restrict__ rdmp) {
  __shared__ __align__(16) unsigned short H[64 * 136];

  const int tid = threadIdx.x;
  const int half = tid >> 6;          // wave id = cout-half (L1/L2), sample-half (L3)
  const int lane = tid & 63;
  const int q = lane >> 4, m = lane & 15;
  const float thresh = (isTrain[0] != 0) ? 0.2f : 0.0f;

  float fA[2], fB[2];
  int cAi[2], cBi[2];
  #pragma unroll
  for (int ks = 0; ks < 2; ++ks) {
    int ch = ks * 4 + q;
    cAi[ks] = (ch <= 2) ? 0 : ((ch <= 4) ? 1 : 2);
    fA[ks]  = (ch == 0 || ch == 5) ? 1.0f :
              (ch == 1 || ch == 6) ? 16.0f :
              (ch == 2 || ch == 7) ? 256.0f :
              (ch == 3) ? 4.0f : 64.0f;
    cBi[ks] = (ch <= 1) ? 0 : ((ch <= 4) ? 1 : 2);
    fB[ks]  = (ch == 2) ? 1.0f :
              (ch == 0 || ch == 5) ? 4.0f :
              (ch == 3) ? 16.0f :
              (ch == 1 || ch == 6) ? 64.0f : 256.0f;
  }

  bf16x8 bx[4][2];
  bf16x8 dpe0, dpe1;
  float zs[4];
  #pragma unroll
  for (int nt = 0; nt < 4; ++nt) {
    int s = nt * 16 + m;
    int sg = blockIdx.x * 64 + s;
    int pixel = sg >> 2;
    float z = zbufs[sg];
    zs[nt] = z;
    const float* r = ray + (size_t)pixel * 7;
    float t = z / r[6];
    float xv0 = r[0] + r[3] * t, xv1 = r[1] + r[4] * t, xv2 = r[2] + r[5] * t;
    #pragma unroll
    for (int ks = 0; ks < 2; ++ks) {
      float uA = (cAi[ks] == 0) ? xv0 : ((cAi[ks] == 1) ? xv1 : xv2);
      float uB = (cBi[ks] == 0) ? xv0 : ((cBi[ks] == 1) ? xv1 : xv2);
      float sa, ca, sb, cb;
      __sincosf(uA * fA[ks], &sa, &ca);
      __sincosf(uB * fB[ks], &sb, &cb);
      float t2a = sa + sa;
      float sa1 = t2a * ca, ca1 = fmaf(-t2a, sa, 1.0f);
      float t2b = sb + sb;
      float sb1 = t2b * cb, cb1 = fmaf(-t2b, sb, 1.0f);
      if (ks == 1 && q == 3) { sb = xv0; cb = xv1; sb1 = xv2; cb1 = 0.0f; }
      uint4 dv;
      dv.x = pk2bf(sa, ca); dv.y = pk2bf(sa1, ca1);
      dv.z = pk2bf(sb, cb); dv.w = pk2bf(sb1, cb1);
      bx[nt][ks] = u4_to_bf(dv);
    }
    // dir-PE fragment for this wave's two L3 sample groups
    if ((nt >> 1) == half) {
      float dd0 = r[3], dd1 = r[4], dd2 = r[5];
      float ss[4], cc[4];
      #pragma unroll
      for (int ii = 0; ii < 4; ++ii) {
        int a = q * 4 + ii - 2;                 // angle index; <0 or >11 = dummy
        int ac = (a < 0 || a > 11) ? 0 : a;
        int c = ac >> 2;
        float base = (c == 0) ? dd0 : ((c == 1) ? dd1 : dd2);
        float fs = (float)(1 << (ac & 3));
        __sincosf(base * fs, &ss[ii], &cc[ii]);
      }
      uint4 dv;
      if (q == 0) {
        dv.x = pk2bf(dd0, dd1);
        dv.y = pk2bf(dd2, 0.0f);
        dv.z = pk2bf(ss[2], cc[2]);
        dv.w = pk2bf(ss[3], cc[3]);
      } else if (q == 3) {
        dv.x = pk2bf(ss[0], cc[0]);
        dv.y = pk2bf(ss[1], cc[1]);
        dv.z = 0u; dv.w = 0u;
      } else {
        dv.x = pk2bf(ss[0], cc[0]);
        dv.y = pk2bf(ss[1], cc[1]);
        dv.z = pk2bf(ss[2], cc[2]);
        dv.w = pk2bf(ss[3], cc[3]);
      }
      if ((nt & 1) == 0) dpe0 = u4_to_bf(dv); else dpe1 = u4_to_bf(dv);
    }
  }
  // L3 sample-half z values (constant-index selects)
  float zL[2];
  zL[0] = (half == 0) ? zs[0] : zs[2];
  zL[1] = (half == 0) ? zs[1] : zs[3];

  // ---- layer 1: this wave's cout-half ----
  {
    floatx4 acc[4][4];
    #pragma unroll
    for (int mt = 0; mt < 4; ++mt) {
      float4 bb = *reinterpret_cast<const float4*>(b1 + (half * 4 + mt) * 16 + q * 4);
      #pragma unroll
      for (int nt = 0; nt < 4; ++nt) {
        acc[mt][nt][0] = bb.x; acc[mt][nt][1] = bb.y;
        acc[mt][nt][2] = bb.z; acc[mt][nt][3] = bb.w;
      }
    }
    #pragma unroll
    for (int ks = 0; ks < 2; ++ks) {
      #pragma unroll
      for (int mt = 0; mt < 4; ++mt) {
        int mtg = half * 4 + mt;
        bf16x8 a = *reinterpret_cast<const bf16x8*>(w1A + (((mtg << 1) + ks) << 9) + lane * 8);
        #pragma unroll
        for (int nt = 0; nt < 4; ++nt)
          acc[mt][nt] = mfma16(a, bx[nt][ks], acc[mt][nt]);
      }
    }
    #pragma unroll
    for (int nt = 0; nt < 4; ++nt) {
      uint4* base = reinterpret_cast<uint4*>(&H[(nt * 16 + m) * 136 + q * 32 + half * 16]);
      #pragma unroll
      for (int g = 0; g < 2; ++g) {
        uint4 v;
        v.x = pk2bf(fmaxf(acc[2*g][nt][0], 0.0f),   fmaxf(acc[2*g][nt][1], 0.0f));
        v.y = pk2bf(fmaxf(acc[2*g][nt][2], 0.0f),   fmaxf(acc[2*g][nt][3], 0.0f));
        v.z = pk2bf(fmaxf(acc[2*g+1][nt][0], 0.0f), fmaxf(acc[2*g+1][nt][1], 0.0f));
        v.w = pk2bf(fmaxf(acc[2*g+1][nt][2], 0.0f), fmaxf(acc[2*g+1][nt][3], 0.0f));
        base[g] = v;
      }
    }
  }
  __syncthreads();   // h1 complete before L2 reads

  // ---- layer 2: this wave's cout-half; epilogue staged in regs ----
  {
    uint4 keep[4][2];
    {
      floatx4 acc[4][4];
      #pragma unroll
      for (int mt = 0; mt < 4; ++mt) {
        float4 bb = *reinterpret_cast<const float4*>(b2 + (half * 4 + mt) * 16 + q * 4);
        #pragma unroll
        for (int nt = 0; nt < 4; ++nt) {
          acc[mt][nt][0] = bb.x; acc[mt][nt][1] = bb.y;
          acc[mt][nt][2] = bb.z; acc[mt][nt][3] = bb.w;
        }
      }
      #pragma unroll 1
      for (int ks = 0; ks < 4; ++ks) {
        bf16x8 bf[4];
        #pragma unroll
        for (int nt = 0; nt < 4; ++nt)
          bf[nt] = lds_frag(H + (nt * 16 + m) * 136 + ks * 32 + q * 8);
        #pragma unroll
        for (int mt = 0; mt < 4; ++mt) {
          int mtg = half * 4 + mt;
          bf16x8 a = *reinterpret_cast<const bf16x8*>(w2A + (((mtg << 2) + ks) << 9) + lane * 8);
          #pragma unroll
          for (int nt = 0; nt < 4; ++nt)
            acc[mt][nt] = mfma16(a, bf[nt], acc[mt][nt]);
        }
      }
      #pragma unroll
      for (int nt = 0; nt < 4; ++nt) {
        #pragma unroll
        for (int g = 0; g < 2; ++g) {
          uint4 v;
          v.x = pk2bf(fmaxf(acc[2*g][nt][0], 0.0f),   fmaxf(acc[2*g][nt][1], 0.0f));
          v.y = pk2bf(fmaxf(acc[2*g][nt][2], 0.0f),   fmaxf(acc[2*g][nt][3], 0.0f));
          v.z = pk2bf(fmaxf(acc[2*g+1][nt][0], 0.0f), fmaxf(acc[2*g+1][nt][1], 0.0f));
          v.w = pk2bf(fmaxf(acc[2*g+1][nt][2], 0.0f), fmaxf(acc[2*g+1][nt][3], 0.0f));
          keep[nt][g] = v;
        }
      }
    }
    __syncthreads();   // all h1 reads done before overwrite
    #pragma unroll
    for (int nt = 0; nt < 4; ++nt)
      #pragma unroll
      for (int g = 0; g < 2; ++g)
        *reinterpret_cast<uint4*>(&H[(nt * 16 + m) * 136 + q * 32 + half * 16 + g * 8]) = keep[nt][g];
  }
  __syncthreads();   // h2 complete before L3 reads

  // ---- layer 3: both cout-tiles, this wave's sample-half; K = 128 hidden + 27 dpe ----
  {
    floatx4 acc[2][2];   // [mt][nt2]
    #pragma unroll
    for (int mt = 0; mt < 2; ++mt) {
      float4 bb3 = *reinterpret_cast<const float4*>(b3 + mt * 16 + q * 4);
      #pragma unroll
      for (int nt2 = 0; nt2 < 2; ++nt2) {
        acc[mt][nt2][0] = bb3.x; acc[mt][nt2][1] = bb3.y;
        acc[mt][nt2][2] = bb3.z; acc[mt][nt2][3] = bb3.w;
      }
    }
    #pragma unroll
    for (int mt = 0; mt < 2; ++mt) {      // dpe K-block (ks slot 4)
      bf16x8 a = *reinterpret_cast<const bf16x8*>(w3A + (((mt << 3) + 4) << 9) + lane * 8);
      acc[mt][0] = mfma16(a, dpe0, acc[mt][0]);
      acc[mt][1] = mfma16(a, dpe1, acc[mt][1]);
    }
    #pragma unroll 2
    for (int ks = 0; ks < 4; ++ks) {
      bf16x8 bf[2];
      #pragma unroll
      for (int nt2 = 0; nt2 < 2; ++nt2)
        bf[nt2] = lds_frag(H + ((half * 2 + nt2) * 16 + m) * 136 + ks * 32 + q * 8);
      #pragma unroll
      for (int mt = 0; mt < 2; ++mt) {
        bf16x8 a = *reinterpret_cast<const bf16x8*>(w3A + (((mt << 3) + ks) << 9) + lane * 8);
        #pragma unroll
        for (int nt2 = 0; nt2 < 2; ++nt2)
          acc[mt][nt2] = mfma16(a, bf[nt2], acc[mt][nt2]);
      }
    }
    #pragma unroll
    for (int nt2 = 0; nt2 < 2; ++nt2) {
      int s = (half * 2 + nt2) * 16 + m;
      float mk = (zL[nt2] > thresh) ? 1.0f : 0.0f;
      unsigned short* dst = rdmp + (size_t)blockIdx.x * 2048 + s * 32 + q * 4;
      #pragma unroll
      for (int mt = 0; mt < 2; ++mt) {
        uint2 pk;
        pk.x = pk2bf(acc[mt][nt2][0] * mk, acc[mt][nt2][1] * mk);
        pk.y = pk2bf(acc[mt][nt2][2] * mk, acc[mt][nt2][3] * mk);
        *reinterpret_cast<uint2*>(dst + mt * 16) = pk;
      }
    }
  }
}

// ---------------- NHWC 3x3 conv via MFMA, 16x8 tile, 8 waves + B-prefetch ----
// R20 lesson: the explicit b0/b1 ping-pong is load-bearing -- full unroll let
// the compiler minimize VGPR (56) by serializing B-loads: 304.6 -> 333 µs.
// Keep rolled ping-pong. R21: NT=1 convs (conv3/conv4) have live set ~75-85
// VGPR (b-pp 24 + a 24 + acc 16), so MINW=6 (cap 85) -> 3 blocks/CU = 24
// waves (was 16). NT=2 convs stay MINW=4 (live ~116; cap 85 would spill).
template<int CIN, int COUT, int MODE, int MINW>
__global__ __launch_bounds__(512, MINW) void conv3x3(
    const unsigned short* __restrict__ in, const unsigned short* __restrict__ wt,
    const float* __restrict__ bias, const unsigned short* __restrict__ rdmp,
    unsigned short* __restrict__ out) {
  constexpr int CP  = CIN + 8;
  constexpr int CH8 = CIN / 8;
  constexpr int KC  = CIN / 32;
  constexpr int NT  = COUT / 64;
  constexpr int GROUPS = KC * 3;
  __shared__ __align__(16) unsigned short lds_in[10 * 18 * CP];

  const int tid = threadIdx.x;
  const int x0 = blockIdx.x * 16, y0 = blockIdx.y * 8;

  for (int i = tid; i < 180 * CH8; i += 512) {
    int pix = i / CH8, part = i - pix * CH8;
    int xx = pix % 18, yy = pix / 18;
    int gx = x0 - 1 + xx, gy = y0 - 1 + yy;
    ushort8 v = {0, 0, 0, 0, 0, 0, 0, 0};
    if (gx >= 0 && gx < IMGW && gy >= 0 && gy < IMGW)
      v = *reinterpret_cast<const ushort8*>(in + ((size_t)(gy * IMGW + gx)) * CIN + part * 8);
    *reinterpret_cast<ushort8*>(&lds_in[pix * CP + part * 8]) = v;
  }
  __syncthreads();

  const int wave = tid >> 6, lane = tid & 63, q = lane >> 4, m = lane & 15;
  const int cw = wave & 3;       // cout quarter
  const int rw = wave >> 2;      // row half: output rows rw*4 .. rw*4+3
  floatx4 acc[4][NT] = {};

  auto loadB = [&](int g, bf16x8 (&bb)[3][NT]) {
    int kc = g / 3, dx = g - kc * 3;
    #pragma unroll
    for (int dy = 0; dy < 3; ++dy) {
      int ks = (dy * 3 + dx) * KC + kc;
      #pragma unroll
      for (int nt = 0; nt < NT; ++nt)
        bb[dy][nt] = *reinterpret_cast<const bf16x8*>(
            wt + ((((size_t)ks * 4 + cw) * NT + nt) << 9) + lane * 8);
    }
  };
  auto compute = [&](int g, bf16x8 (&bb)[3][NT]) {
    int kc = g / 3, dx = g - kc * 3;
    bf16x8 a[6];
    #pragma unroll
    for (int rr = 0; rr < 6; ++rr)
      a[rr] = lds_frag(&lds_in[((rw * 4 + rr) * 18 + m + dx) * CP + kc * 32 + q * 8]);
    #pragma unroll
    for (int dy = 0; dy < 3; ++dy)
      #pragma unroll
      for (int nt = 0; nt < NT; ++nt)
        #pragma unroll
        for (int mt = 0; mt < 4; ++mt)
          acc[mt][nt] = mfma16(a[mt + dy], bb[dy][nt], acc[mt][nt]);
  };

  bf16x8 b0[3][NT], b1[3][NT];
  loadB(0, b0);
  #pragma unroll 1
  for (int g = 0; g < GROUPS; g += 2) {
    loadB(g + 1, b1);                     // in flight during compute(g)
    compute(g, b0);
    if (g + 2 < GROUPS) loadB(g + 2, b0); // in flight during compute(g+1)
    compute(g + 1, b1);
  }

  const int co0 = cw * (COUT / 4);
  #pragma unroll
  for (int mt = 0; mt < 4; ++mt) {
    int y = y0 + rw * 4 + mt;
    #pragma unroll
    for (int nt = 0; nt < NT; ++nt) {
      int co = co0 + nt * 16 + m;
      float bb = bias[co];
      #pragma unroll
      for (int r = 0; r < 4; ++r) {
        int pixel = y * IMGW + x0 + q * 4 + r;
        float v = acc[mt][nt][r] + bb;
        if (MODE == 0) {
          v = fmaxf(v, 0.0f);
        } else {
          v = 1.0f / (1.0f + __expf(-v));
          v *= bf2f(rdmp[(size_t)pixel * 128 + co]);
        }
        out[(size_t)pixel * COUT + co] = f2bf(v);
      }
    }
  }
}

// ---------------- final 64->3 conv + sigmoid via MFMA (R17) ----------------
__global__ __launch_bounds__(256) void uconv3_kernel(
    const unsigned short* __restrict__ u2, const unsigned short* __restrict__ wt,
    const float* __restrict__ b, float* __restrict__ out) {
  __shared__ __align__(16) unsigned short lds_in[180 * 72];
  const int tid = threadIdx.x;
  const int x0 = blockIdx.x * 16, y0 = blockIdx.y * 8;
  for (int i = tid; i < 180 * 8; i += 256) {
    int pix = i >> 3, part = i & 7;
    int xx = pix % 18, yy = pix / 18;
    int gx = x0 - 1 + xx, gy = y0 - 1 + yy;
    ushort8 v = {0, 0, 0, 0, 0, 0, 0, 0};
    if (gx >= 0 && gx < IMGW && gy >= 0 && gy < IMGW)
      v = *reinterpret_cast<const ushort8*>(u2 + (size_t)(gy * IMGW + gx) * 64 + part * 8);
    *reinterpret_cast<ushort8*>(&lds_in[pix * 72 + part * 8]) = v;
  }
  __syncthreads();
  const int wave = tid >> 6, lane = tid & 63, q = lane >> 4, m = lane & 15;
  floatx4 acc[2] = {};
  #pragma unroll 1
  for (int g = 0; g < 6; ++g) {
    int kc = g / 3, dx = g - kc * 3;
    bf16x8 bb[3];
    #pragma unroll
    for (int dy = 0; dy < 3; ++dy) {
      int ks = (dy * 3 + dx) * 2 + kc;
      bb[dy] = *reinterpret_cast<const bf16x8*>(wt + (ks << 9) + lane * 8);
    }
    bf16x8 a[4];
    #pragma unroll
    for (int rr = 0; rr < 4; ++rr)
      a[rr] = lds_frag(&lds_in[((wave * 2 + rr) * 18 + m + dx) * 72 + kc * 32 + q * 8]);
    #pragma unroll
    for (int dy = 0; dy < 3; ++dy)
      #pragma unroll
      for (int mt = 0; mt < 2; ++mt)
        acc[mt] = mfma16(a[mt + dy], bb[dy], acc[mt]);
  }
  if (m < 3) {
    float bbv = b[m];
    #pragma unroll
    for (int mt = 0; mt < 2; ++mt) {
      int y = y0 + wave * 2 + mt;
      #pragma unroll
      for (int r = 0; r < 4; ++r) {
        int pixel = y * IMGW + x0 + q * 4 + r;
        out[(size_t)pixel * 3 + m] = 1.0f / (1.0f + __expf(-(acc[mt][r] + bbv)));
      }
    }
  }
}

extern "C" void kernel_launch(void* const* d_in, const int* in_sizes, int n_in,
                              void* d_out, int out_size, void* d_ws, size_t ws_size,
                              hipStream_t stream) {
  (void)in_sizes; (void)n_in; (void)out_size; (void)ws_size;
  const float* zbufs = (const float*)d_in[0];
  const float* ray   = (const float*)d_in[1];
  const int* isTrain = (const int*)d_in[4];
  const float* w1 = (const float*)d_in[6];
  const float* b1 = (const float*)d_in[7];
  const float* w2 = (const float*)d_in[8];
  const float* b2 = (const float*)d_in[9];
  const float* w3 = (const float*)d_in[10];
  const float* b3 = (const float*)d_in[11];
  const float* mpn_w1 = (const float*)d_in[12];
  const float* mpn_b1 = (const float*)d_in[13];
  const float* mpn_w2 = (const float*)d_in[14];
  const float* mpn_b2 = (const float*)d_in[15];
  const float* uw1 = (const float*)d_in[16];
  const float* ub1 = (const float*)d_in[17];
  const float* uw2 = (const float*)d_in[18];
  const float* ub2 = (const float*)d_in[19];
  const float* uw3 = (const float*)d_in[20];
  const float* ub3 = (const float*)d_in[21];
  float* out = (float*)d_out;

  unsigned char* ws = (unsigned char*)d_ws;
  size_t off = 0;
  auto alloc = [&](size_t bytes) -> void* {
    void* p = ws + off; off = (off + bytes + 255) & ~(size_t)255; return p;
  };
  unsigned short* w1A  = (unsigned short*)alloc(8192 * 2);
  unsigned short* w2A  = (unsigned short*)alloc(16384 * 2);
  unsigned short* w3A  = (unsigned short*)alloc(8192 * 2);
  unsigned short* cw1  = (unsigned short*)alloc((size_t)128 * 1152 * 2);
  unsigned short* cw2  = (unsigned short*)alloc((size_t)128 * 1152 * 2);
  unsigned short* cu1  = (unsigned short*)alloc((size_t)64 * 1152 * 2);
  unsigned short* cu2  = (unsigned short*)alloc((size_t)64 * 576 * 2);
  unsigned short* cu3  = (unsigned short*)alloc((size_t)9216 * 2);
  unsigned short* rdmp = (unsigned short*)alloc((size_t)NPIX * 128 * 2);
  unsigned short* t1   = (unsigned short*)alloc((size_t)NPIX * 128 * 2);
  unsigned short* fuse = (unsigned short*)alloc((size_t)NPIX * 128 * 2);
  unsigned short* u1 = t1;            // t1 dead after conv2
  unsigned short* u2 = rdmp;          // rdmp dead after conv2 (fuse epilogue)

  prep_all<<<1736, 256, 0, stream>>>(w1, w2, w3, mpn_w1, mpn_w2, uw1, uw2, uw3,
                                     w1A, w2A, w3A, cw1, cw2, cu1, cu2, cu3);
  mlp_kernel<<<NPIX * 4 / 64, 128, 0, stream>>>(zbufs, ray, isTrain, b1, b2, b3,
                                                w1A, w2A, w3A, rdmp);

  dim3 cgrid(IMGW / 16, IMGW / 8);
  conv3x3<128, 128, 0, 4><<<cgrid, 512, 0, stream>>>(rdmp, cw1, mpn_b1, nullptr, t1);
  conv3x3<128, 128, 1, 4><<<cgrid, 512, 0, stream>>>(t1, cw2, mpn_b2, rdmp, fuse);
  conv3x3<128, 64, 0, 6><<<cgrid, 512, 0, stream>>>(fuse, cu1, ub1, nullptr, u1);
  conv3x3<64, 64, 0, 6><<<cgrid, 512, 0, stream>>>(u1, cu2, ub2, nullptr, u2);
  uconv3_kernel<<<cgrid, 256, 0, stream>>>(u2, cu3, ub3, out);
}